// Round 5
// baseline (521.898 us; speedup 1.0000x reference)
//
#include <hip/hip_runtime.h>
#include <hip/hip_bf16.h>

#define BB 4
#define SS 2048
#define FF 128
#define DD 128
#define HD 512
#define OUTD 128
#define BH 16
#define NSL 0.01f
#define NC 258      // prefix columns: 128 (u*hp) + 128 (v*hp) + Su + Sv
#define NCH 32      // chunks of 64 ranks
#define CHK 64

typedef __hip_bfloat16 bf16;
typedef short bf16x8 __attribute__((ext_vector_type(8)));
typedef float f32x4 __attribute__((ext_vector_type(4)));

// ---------------- workspace layout (in floats), total ~70 MB ----------------
constexpr size_t OFF_HPF  = 0;                                   // hp f32 [B*S][512]
constexpr size_t OFF_E1   = OFF_HPF + (size_t)BB*SS*HD;          // [bh][S]
constexpr size_t OFF_M2   = OFF_E1 + (size_t)BH*SS;              // [bh] (padded 64)
constexpr size_t OFF_U    = OFF_M2 + 64;
constexpr size_t OFF_V    = OFF_U + (size_t)BH*SS;
constexpr size_t OFF_SIG  = OFF_V + (size_t)BH*SS;               // delta-sorted perm (int)
constexpr size_t OFF_RARR = OFF_SIG + (size_t)BH*SS;             // crossover rank per ROW i (int)
constexpr size_t OFF_WV   = OFF_RARR + (size_t)BH*SS;            // w1[4][128] then w2[4][128]
constexpr size_t OFF_PL   = OFF_WV + 1024;                       // [bh][2049][NC] chunk-local prefix
constexpr size_t OFF_CS   = OFF_PL + (size_t)BH*2049*NC;         // [bh][NCH][NC] chunk sums
constexpr size_t OFF_O    = OFF_CS + (size_t)BH*NCH*NC;          // [bh][NCH][NC] chunk offsets (L2)
constexpr size_t OFF_TOT  = OFF_O + (size_t)BH*NCH*NC;           // [bh][NC] totals
constexpr size_t OFF_CTX  = OFF_TOT + (size_t)BH*NC;             // ctx f32 [B*S][512]

// split f32 x8 into hi/lo bf16 fragments (hi = rne(x), lo = rne(x - hi))
__device__ inline void load8_split(const float* __restrict__ p, bf16x8& hi, bf16x8& lo) {
  f32x4 x0 = *(const f32x4*)p;
  f32x4 x1 = *(const f32x4*)(p + 4);
#pragma unroll
  for (int e = 0; e < 8; ++e) {
    float x = (e < 4) ? x0[e] : x1[e - 4];
    __hip_bfloat16 hb = __float2bfloat16(x);
    float hf = __bfloat162float(hb);
    __hip_bfloat16 lb = __float2bfloat16(x - hf);
    hi[e] = (short)__bfloat16_as_ushort(hb);
    lo[e] = (short)__bfloat16_as_ushort(lb);
  }
}

// K0: head vectors w1[h] = W_w[h]^T a1, w2[h] = W_w[h]^T a2  (8 x 128 GEMV, tiny)
__global__ __launch_bounds__(128) void k0_wvec(const float* __restrict__ Ww, const float* __restrict__ aw,
                                               float* __restrict__ wv) {
  int which = blockIdx.x >> 2, hh = blockIdx.x & 3;   // 8 blocks
  int f = threadIdx.x;
  float acc = 0.f;
#pragma unroll 4
  for (int d = 0; d < DD; ++d)
    acc += Ww[(size_t)(hh*DD + d)*FF + f] * aw[which*DD + d];
  wv[which*512 + hh*DD + f] = acc;
}

// K1: hp = h @ W_w^T (+W_b). 16x16 wave tiles, hi/lo-split bf16 MFMA (~f32 accuracy).
__global__ __launch_bounds__(256) void k1_hp(const float* __restrict__ h, const float* __restrict__ Ww,
                                             const float* __restrict__ Wb, float* __restrict__ hpf) {
  int wid = threadIdx.x >> 6, lane = threadIdx.x & 63;
  int tile = blockIdx.x * 4 + wid;          // 16384 tiles = 512 x 32
  int mt = tile >> 5, nt = tile & 31;
  int s0 = mt * 16, n0 = nt * 16;
  int row = lane & 15, g = lane >> 4;
  const float* pa = h  + (size_t)(s0 + row) * FF + g * 8;
  const float* pb = Ww + (size_t)(n0 + row) * FF + g * 8;
  f32x4 acc = {0.f,0.f,0.f,0.f};
#pragma unroll
  for (int ks = 0; ks < 4; ++ks) {
    bf16x8 ah, al, bh_, bl;
    load8_split(pa + ks*32, ah, al);
    load8_split(pb + ks*32, bh_, bl);
    acc = __builtin_amdgcn_mfma_f32_16x16x32_bf16(ah, bh_, acc, 0, 0, 0);
    acc = __builtin_amdgcn_mfma_f32_16x16x32_bf16(ah, bl,  acc, 0, 0, 0);
    acc = __builtin_amdgcn_mfma_f32_16x16x32_bf16(al, bh_, acc, 0, 0, 0);
  }
  int col = lane & 15;
  float bias = Wb[n0 + col];
#pragma unroll
  for (int r = 0; r < 4; ++r) {
    int orow = g*4 + r;   // C/D layout: col=lane&15, row=4*(lane>>4)+reg
    hpf[(size_t)(s0 + orow) * HD + n0 + col] = acc[r] + bias;
  }
}

// K2bc: per bh: e1/e2 from h and head vectors -> masked max -> u,v -> bitonic sort (e2,idx)
// -> per-row crossover ranks rarr[i] via parallel binary search.
__global__ __launch_bounds__(1024) void k2bc(const float* __restrict__ h, const int* __restrict__ mask,
                                             const float* __restrict__ wv, const float* __restrict__ abp,
                                             float* __restrict__ e1g, float* __restrict__ m2out,
                                             float* __restrict__ u, float* __restrict__ v,
                                             int* __restrict__ sig, int* __restrict__ rarr) {
  int bh = blockIdx.x; int b = bh >> 2, hh = bh & 3;
  int tid = threadIdx.x;
  int wvid = tid >> 6, lane = tid & 63;     // 16 waves
  __shared__ float red[1024];
  __shared__ float e1s[SS];
  __shared__ float va[SS];                  // key: e2
  __shared__ int ia[SS];
  float w1a = wv[hh*DD + lane],       w1b = wv[hh*DD + lane + 64];
  float w2a = wv[512 + hh*DD + lane], w2b = wv[512 + hh*DD + lane + 64];
  const float* hbase = h + (size_t)b*SS*FF;
  for (int s = wvid; s < SS; s += 16) {
    float xa = hbase[(size_t)s*FF + lane];
    float xb = hbase[(size_t)s*FF + lane + 64];
    float r1 = xa*w1a + xb*w1b;
    float r2 = xa*w2a + xb*w2b;
    for (int o = 32; o; o >>= 1) { r1 += __shfl_down(r1, o); r2 += __shfl_down(r2, o); }
    if (lane == 0) { e1s[s] = r1; va[s] = r2; ia[s] = s; }
  }
  __syncthreads();
  // masked max of e2
  float mx = -1e30f;
  for (int j = tid; j < SS; j += 1024)
    if (!mask[b*SS + j]) mx = fmaxf(mx, va[j]);
  red[tid] = mx; __syncthreads();
  for (int st = 512; st; st >>= 1) {
    if (tid < st) red[tid] = fmaxf(red[tid], red[tid + st]);
    __syncthreads();
  }
  float m2 = red[0];
  if (tid == 0) m2out[bh] = m2;
  // u, v, e1 global
  for (int j = tid; j < SS; j += 1024) {
    float d = va[j] - m2;
    int mk = mask[b*SS + j];
    u[(size_t)bh*SS + j] = mk ? 0.f : expf(d);
    v[(size_t)bh*SS + j] = mk ? 0.f : expf(NSL * d);
    e1g[(size_t)bh*SS + j] = e1s[j];
  }
  __syncthreads();
  // bitonic sort (va, ia) ascending
  for (int k = 2; k <= SS; k <<= 1) {
    for (int jj = k >> 1; jj > 0; jj >>= 1) {
      for (int p = tid; p < SS; p += 1024) {
        int l = p ^ jj;
        if (l > p) {
          bool up = ((p & k) == 0);
          float vp = va[p], vl = va[l];
          if ((vp > vl) == up) {
            va[p] = vl; va[l] = vp;
            int t = ia[p]; ia[p] = ia[l]; ia[l] = t;
          }
        }
      }
      __syncthreads();
    }
  }
  float ab = abp[0];
  // sig + per-ROW crossover rank: r(i) = lower_bound(va, -e1[i]-ab)
  for (int i = tid; i < SS; i += 1024) {
    sig[(size_t)bh*SS + i] = ia[i];
    float key = -e1s[i] - ab;
    int lo = 0, hi = SS;
    while (lo < hi) { int mid = (lo + hi) >> 1; if (va[mid] < key) lo = mid + 1; else hi = mid; }
    rarr[(size_t)bh*SS + i] = lo;
  }
}

// K3a: chunk-local prefix sums over sorted ranks (CHK=64). LDS-staged sig/u/v for the chunk.
__global__ __launch_bounds__(320) void k3a_prefix(const float* __restrict__ hpf, const float* __restrict__ u,
                                                  const float* __restrict__ v, const int* __restrict__ sig,
                                                  float* __restrict__ PL, float* __restrict__ CS) {
  int bh = blockIdx.x >> 5;
  int ch = blockIdx.x & (NCH - 1);
  int c = threadIdx.x;
  int b = bh >> 2, hh = bh & 3;
  __shared__ int   js[CHK];
  __shared__ float us[CHK], vs[CHK];
  if (c < CHK) {
    int j = sig[(size_t)bh*SS + ch*CHK + c];
    js[c] = j;
    us[c] = u[(size_t)bh*SS + j];
    vs[c] = v[(size_t)bh*SS + j];
  }
  __syncthreads();
  if (c >= NC) return;
  if (ch == 0) PL[((size_t)bh*2049 + 0)*NC + c] = 0.f;   // rank-0 prefix = 0
  const float* hb = hpf + (size_t)b*SS*HD + hh*DD;
  float acc = 0.f;
  size_t plbase = ((size_t)bh*2049 + ch*CHK + 1)*NC + c;
#pragma unroll 8
  for (int r = 0; r < CHK; ++r) {
    float term;
    if (c < 128)      term = us[r] * hb[(size_t)js[r]*HD + c];
    else if (c < 256) term = vs[r] * hb[(size_t)js[r]*HD + (c-128)];
    else if (c == 256) term = us[r];
    else              term = vs[r];
    acc += term;
    PL[plbase + (size_t)r*NC] = acc;
  }
  CS[((size_t)bh*NCH + ch)*NC + c] = acc;
}

// K3b: exclusive scan of chunk sums -> offsets, and totals
__global__ __launch_bounds__(320) void k3b_scan(const float* __restrict__ CS, float* __restrict__ O,
                                                float* __restrict__ Tot) {
  int bh = blockIdx.x; int c = threadIdx.x;
  if (c >= NC) return;
  float acc = 0.f;
  for (int ch = 0; ch < NCH; ++ch) {
    O[((size_t)bh*NCH + ch)*NC + c] = acc;
    acc += CS[((size_t)bh*NCH + ch)*NC + c];
  }
  Tot[(size_t)bh*NC + c] = acc;
}

// K4: natural row order (sequential attn/ctx writes); r precomputed per row (rarr).
// Streams attn rows with non-temporal stores.
__global__ __launch_bounds__(256) void k4_main(const float* __restrict__ e1, const float* __restrict__ m2arr,
                                               const float* __restrict__ u, const float* __restrict__ v,
                                               const float* __restrict__ PL, const float* __restrict__ O,
                                               const float* __restrict__ Tot,
                                               const float* __restrict__ abp,
                                               const int* __restrict__ rarr,
                                               float* __restrict__ ctx, float* __restrict__ attn) {
  int bh = blockIdx.x >> 6;      // 64 i-blocks of 32 rows
  int ib = blockIdx.x & 63;
  int b = bh >> 2, hh = bh & 3;
  __shared__ float u_s[SS];
  __shared__ float v_s[SS];
  __shared__ float tot_s[NC];
  for (int j = threadIdx.x; j < SS; j += 256) {
    u_s[j] = u[(size_t)bh*SS + j];
    v_s[j] = v[(size_t)bh*SS + j];
  }
  for (int c0 = threadIdx.x; c0 < NC; c0 += 256) tot_s[c0] = Tot[(size_t)bh*NC + c0];
  __syncthreads();
  int wid = threadIdx.x >> 6, lane = threadIdx.x & 63;
  float m2 = m2arr[bh];
  float ab = abp[0];
  float SuT = tot_s[256];
  for (int rr = wid; rr < 32; rr += 4) {
    int i = ib*32 + rr;
    int r = rarr[(size_t)bh*SS + i];
    float t = e1[(size_t)bh*SS + i] + ab + m2;
    float rm = t > 0.f ? t : NSL*t;             // = leakyrelu(t) = exact row max
    float alpha = expf(t - rm);
    float beta  = expf(NSL*t - rm);
    float tau = -t;
    int ch = (r == 0) ? 0 : ((r - 1) >> 6);
    const float* PLrow = PL + ((size_t)bh*2049 + r)*NC;
    const float* Orow  = O  + ((size_t)bh*NCH + ch)*NC;
    float SU = PLrow[256] + Orow[256];
    float SV = PLrow[257] + Orow[257];
    float denom = alpha * (SuT - SU) + beta * SV;
    float inv = 1.f / denom;
    float ad = alpha * inv, bd = beta * inv;
    // ctx from prefix lookups
#pragma unroll
    for (int d0 = 0; d0 < 2; ++d0) {
      int d = lane + 64*d0;
      float fu = PLrow[d]       + Orow[d];
      float fv = PLrow[128 + d] + Orow[128 + d];
      float cv = (alpha * (tot_s[d] - fu) + beta * fv) * inv;
      ctx[(size_t)(b*SS + i)*HD + hh*DD + d] = cv;
    }
    float utau = expf(tau);      // piece predicate: u_j >= utau  <=>  delta_j >= tau (monotone)
    float* orow = attn + ((size_t)bh*SS + i)*SS;
#pragma unroll 2
    for (int it = 0; it < 8; ++it) {
      int j0 = it*256 + lane*4;
      f32x4 uu = *(const f32x4*)&u_s[j0];
      f32x4 vv = *(const f32x4*)&v_s[j0];
      f32x4 av;
#pragma unroll
      for (int e = 0; e < 4; ++e) av[e] = (uu[e] >= utau) ? ad*uu[e] : bd*vv[e];
      __builtin_nontemporal_store(av, (f32x4*)(orow + j0));
    }
  }
}

// K5: out = relu(ctx @ out_w^T + out_b), hi/lo-split bf16 MFMA (~f32 accuracy)
__global__ __launch_bounds__(256) void k5_out(const float* __restrict__ ctx, const float* __restrict__ W2,
                                              const float* __restrict__ b2, float* __restrict__ outp) {
  int wid = threadIdx.x >> 6, lane = threadIdx.x & 63;
  int s0 = blockIdx.x * 16;        // 512 blocks
  int n0 = wid * 32;
  int row = lane & 15, g = lane >> 4;
  const float* pa  = ctx + (size_t)(s0 + row) * HD + g * 8;
  const float* pb0 = W2  + (size_t)(n0 + row) * HD + g * 8;
  const float* pb1 = W2  + (size_t)(n0 + 16 + row) * HD + g * 8;
  f32x4 acc0 = {0.f,0.f,0.f,0.f}, acc1 = {0.f,0.f,0.f,0.f};
  for (int ks = 0; ks < 16; ++ks) {
    bf16x8 ah, al, b0h, b0l, b1h, b1l;
    load8_split(pa  + ks*32, ah,  al);
    load8_split(pb0 + ks*32, b0h, b0l);
    load8_split(pb1 + ks*32, b1h, b1l);
    acc0 = __builtin_amdgcn_mfma_f32_16x16x32_bf16(ah, b0h, acc0, 0,0,0);
    acc0 = __builtin_amdgcn_mfma_f32_16x16x32_bf16(ah, b0l, acc0, 0,0,0);
    acc0 = __builtin_amdgcn_mfma_f32_16x16x32_bf16(al, b0h, acc0, 0,0,0);
    acc1 = __builtin_amdgcn_mfma_f32_16x16x32_bf16(ah, b1h, acc1, 0,0,0);
    acc1 = __builtin_amdgcn_mfma_f32_16x16x32_bf16(ah, b1l, acc1, 0,0,0);
    acc1 = __builtin_amdgcn_mfma_f32_16x16x32_bf16(al, b1h, acc1, 0,0,0);
  }
  int col = lane & 15;
  float bias0 = b2[n0 + col];
  float bias1 = b2[n0 + 16 + col];
#pragma unroll
  for (int r2 = 0; r2 < 4; ++r2) {
    int orow = g*4 + r2;
    float v0 = acc0[r2] + bias0; v0 = v0 > 0.f ? v0 : 0.f;
    float v1 = acc1[r2] + bias1; v1 = v1 > 0.f ? v1 : 0.f;
    outp[(size_t)(s0 + orow)*OUTD + n0 + col]      = v0;
    outp[(size_t)(s0 + orow)*OUTD + n0 + 16 + col] = v1;
  }
}

extern "C" void kernel_launch(void* const* d_in, const int* in_sizes, int n_in,
                              void* d_out, int out_size, void* d_ws, size_t ws_size,
                              hipStream_t stream) {
  const float* h   = (const float*)d_in[0];
  const int* mask  = (const int*)d_in[1];
  const float* Ww  = (const float*)d_in[2];
  const float* Wb  = (const float*)d_in[3];
  const float* aw  = (const float*)d_in[4];
  const float* abp = (const float*)d_in[5];
  const float* W2  = (const float*)d_in[6];
  const float* b2  = (const float*)d_in[7];
  float* ws = (float*)d_ws;
  float* hpf = ws + OFF_HPF;
  float* e1  = ws + OFF_E1;
  float* m2  = ws + OFF_M2;
  float* u   = ws + OFF_U;
  float* v   = ws + OFF_V;
  int*   sig = (int*)(ws + OFF_SIG);
  int*   rarr= (int*)(ws + OFF_RARR);
  float* wv  = ws + OFF_WV;
  float* PL  = ws + OFF_PL;
  float* CS  = ws + OFF_CS;
  float* O   = ws + OFF_O;
  float* Tot = ws + OFF_TOT;
  float* ctx = ws + OFF_CTX;
  float* outp = (float*)d_out;
  float* attn = outp + (size_t)BB*SS*OUTD;

  k0_wvec<<<8, 128, 0, stream>>>(Ww, aw, wv);
  k1_hp<<<4096, 256, 0, stream>>>(h, Ww, Wb, hpf);
  k2bc<<<16, 1024, 0, stream>>>(h, mask, wv, abp, e1, m2, u, v, sig, rarr);
  k3a_prefix<<<BH*NCH, 320, 0, stream>>>(hpf, u, v, sig, PL, CS);
  k3b_scan<<<16, 320, 0, stream>>>(CS, O, Tot);
  k4_main<<<BH*64, 256, 0, stream>>>(e1, m2, u, v, PL, O, Tot, abp, rarr, ctx, attn);
  k5_out<<<512, 256, 0, stream>>>(ctx, W2, b2, outp);
}

// Round 6
// 460.696 us; speedup vs baseline: 1.1328x; 1.1328x over previous
//
#include <hip/hip_runtime.h>
#include <hip/hip_bf16.h>

#define BB 4
#define SS 2048
#define FF 128
#define DD 128
#define HD 512
#define OUTD 128
#define BH 16
#define NSL 0.01f
#define NC 258      // prefix columns: 128 (u*hp) + 128 (v*hp) + Su + Sv
#define NCH 32      // chunks of 64 ranks
#define CHK 64

typedef __hip_bfloat16 bf16;
typedef short bf16x8 __attribute__((ext_vector_type(8)));
typedef float f32x4 __attribute__((ext_vector_type(4)));

// ---------------- workspace layout (in floats), total ~69 MB ----------------
constexpr size_t OFF_HPF  = 0;                                   // hp f32 [B*S][512]
constexpr size_t OFF_E1   = OFF_HPF + (size_t)BB*SS*HD;          // [bh][S]
constexpr size_t OFF_E2   = OFF_E1 + (size_t)BH*SS;              // [bh][S]
constexpr size_t OFF_M2   = OFF_E2 + (size_t)BH*SS;              // [bh] (padded 64)
constexpr size_t OFF_U    = OFF_M2 + 64;
constexpr size_t OFF_V    = OFF_U + (size_t)BH*SS;
constexpr size_t OFF_SIG  = OFF_V + (size_t)BH*SS;               // delta-sorted perm (int)
constexpr size_t OFF_RARR = OFF_SIG + (size_t)BH*SS;             // crossover rank per ROW i (int)
constexpr size_t OFF_WV   = OFF_RARR + (size_t)BH*SS;            // w1[4][128] then w2[4][128]
constexpr size_t OFF_PL   = OFF_WV + 1024;                       // [bh][2049][NC] chunk-local prefix
constexpr size_t OFF_CS   = OFF_PL + (size_t)BH*2049*NC;         // [bh][NCH][NC] chunk sums
constexpr size_t OFF_CTX  = OFF_CS + (size_t)BH*NCH*NC;          // ctx f32 [B*S][512]

// split f32 x8 into hi/lo bf16 fragments (hi = rne(x), lo = rne(x - hi))
__device__ inline void load8_split(const float* __restrict__ p, bf16x8& hi, bf16x8& lo) {
  f32x4 x0 = *(const f32x4*)p;
  f32x4 x1 = *(const f32x4*)(p + 4);
#pragma unroll
  for (int e = 0; e < 8; ++e) {
    float x = (e < 4) ? x0[e] : x1[e - 4];
    __hip_bfloat16 hb = __float2bfloat16(x);
    float hf = __bfloat162float(hb);
    __hip_bfloat16 lb = __float2bfloat16(x - hf);
    hi[e] = (short)__bfloat16_as_ushort(hb);
    lo[e] = (short)__bfloat16_as_ushort(lb);
  }
}

// K0: head vectors w1[h] = W_w[h]^T a1, w2[h] = W_w[h]^T a2  (8 x 128 GEMV, tiny)
__global__ __launch_bounds__(128) void k0_wvec(const float* __restrict__ Ww, const float* __restrict__ aw,
                                               float* __restrict__ wv) {
  int which = blockIdx.x >> 2, hh = blockIdx.x & 3;   // 8 blocks
  int f = threadIdx.x;
  float acc = 0.f;
#pragma unroll 4
  for (int d = 0; d < DD; ++d)
    acc += Ww[(size_t)(hh*DD + d)*FF + f] * aw[which*DD + d];
  wv[which*512 + hh*DD + f] = acc;
}

// K2e: wide e1/e2 from h and head vectors. One wave per (b,s) row; 8 shfl-dots.
__global__ __launch_bounds__(256) void k2_e(const float* __restrict__ h, const float* __restrict__ wv,
                                            float* __restrict__ e1g, float* __restrict__ e2g) {
  int wid = threadIdx.x >> 6, lane = threadIdx.x & 63;
  int g = blockIdx.x * 4 + wid;           // 8192 rows
  int b = g >> 11, s = g & 2047;
  float xa = h[(size_t)g*FF + lane];
  float xb = h[(size_t)g*FF + 64 + lane];
#pragma unroll
  for (int hh = 0; hh < 4; ++hh) {
    float r1 = xa*wv[hh*DD + lane]       + xb*wv[hh*DD + 64 + lane];
    float r2 = xa*wv[512 + hh*DD + lane] + xb*wv[512 + hh*DD + 64 + lane];
    for (int o = 32; o; o >>= 1) { r1 += __shfl_down(r1, o); r2 += __shfl_down(r2, o); }
    if (lane == 0) {
      e1g[(size_t)(b*4 + hh)*SS + s] = r1;
      e2g[(size_t)(b*4 + hh)*SS + s] = r2;
    }
  }
}

// KF: fused heterogeneous launch, 1040 blocks x 1024 threads.
//  blocks [0,1024):  k1 role — hp = h @ W_w^T + W_b, 16 MFMA tiles per block (16 waves).
//  blocks [1024,1040): k2bc role — per bh: masked max -> u,v -> bitonic sort(e2) -> rarr.
// Roles are independent (k1: h,Ww -> hpf; k2bc: e1,e2,mask -> u,v,sig,rarr), so the
// 16 low-occupancy sort blocks hide under the 1024 GEMM blocks.
__global__ __launch_bounds__(1024) void kfused(const float* __restrict__ h, const float* __restrict__ Ww,
                                               const float* __restrict__ Wb, float* __restrict__ hpf,
                                               const float* __restrict__ e1g, const float* __restrict__ e2g,
                                               const int* __restrict__ mask, const float* __restrict__ abp,
                                               float* __restrict__ m2out, float* __restrict__ u,
                                               float* __restrict__ v, int* __restrict__ sig,
                                               int* __restrict__ rarr) {
  __shared__ float red[1024];
  __shared__ float va[SS];
  __shared__ int   ia[SS];
  int tid = threadIdx.x;
  if (blockIdx.x < 1024) {
    // ---- k1 role ----
    int wid = tid >> 6, lane = tid & 63;
    int tile = blockIdx.x * 16 + wid;       // 16384 tiles = 512 x 32
    int mt = tile >> 5, nt = tile & 31;
    int s0 = mt * 16, n0 = nt * 16;
    int row = lane & 15, g = lane >> 4;
    const float* pa = h  + (size_t)(s0 + row) * FF + g * 8;
    const float* pb = Ww + (size_t)(n0 + row) * FF + g * 8;
    f32x4 acc = {0.f,0.f,0.f,0.f};
#pragma unroll
    for (int ks = 0; ks < 4; ++ks) {
      bf16x8 ah, al, bh_, bl;
      load8_split(pa + ks*32, ah, al);
      load8_split(pb + ks*32, bh_, bl);
      acc = __builtin_amdgcn_mfma_f32_16x16x32_bf16(ah, bh_, acc, 0, 0, 0);
      acc = __builtin_amdgcn_mfma_f32_16x16x32_bf16(ah, bl,  acc, 0, 0, 0);
      acc = __builtin_amdgcn_mfma_f32_16x16x32_bf16(al, bh_, acc, 0, 0, 0);
    }
    int col = lane & 15;
    float bias = Wb[n0 + col];
#pragma unroll
    for (int r = 0; r < 4; ++r) {
      int orow = g*4 + r;   // C/D layout: col=lane&15, row=4*(lane>>4)+reg
      hpf[(size_t)(s0 + orow) * HD + n0 + col] = acc[r] + bias;
    }
    return;
  }
  // ---- k2bc role ----
  int bh = blockIdx.x - 1024; int b = bh >> 2;
  // stage e2 as sort keys
  for (int j = tid; j < SS; j += 1024) { va[j] = e2g[(size_t)bh*SS + j]; ia[j] = j; }
  __syncthreads();
  // masked max of e2
  float mx = -1e30f;
  for (int j = tid; j < SS; j += 1024)
    if (!mask[b*SS + j]) mx = fmaxf(mx, va[j]);
  red[tid] = mx; __syncthreads();
  for (int st = 512; st; st >>= 1) {
    if (tid < st) red[tid] = fmaxf(red[tid], red[tid + st]);
    __syncthreads();
  }
  float m2 = red[0];
  if (tid == 0) m2out[bh] = m2;
  // u, v (index-aligned, before sort mutates va)
  for (int j = tid; j < SS; j += 1024) {
    float d = va[j] - m2;
    int mk = mask[b*SS + j];
    u[(size_t)bh*SS + j] = mk ? 0.f : expf(d);
    v[(size_t)bh*SS + j] = mk ? 0.f : expf(NSL * d);
  }
  __syncthreads();
  // bitonic sort (va, ia) ascending
  for (int k = 2; k <= SS; k <<= 1) {
    for (int jj = k >> 1; jj > 0; jj >>= 1) {
      for (int p = tid; p < SS; p += 1024) {
        int l = p ^ jj;
        if (l > p) {
          bool up = ((p & k) == 0);
          float vp = va[p], vl = va[l];
          if ((vp > vl) == up) {
            va[p] = vl; va[l] = vp;
            int t = ia[p]; ia[p] = ia[l]; ia[l] = t;
          }
        }
      }
      __syncthreads();
    }
  }
  float ab = abp[0];
  // sig + per-ROW crossover rank: r(i) = lower_bound(va, -e1[i]-ab)
  for (int i = tid; i < SS; i += 1024) {
    sig[(size_t)bh*SS + i] = ia[i];
    float key = -e1g[(size_t)bh*SS + i] - ab;
    int lo = 0, hi = SS;
    while (lo < hi) { int mid = (lo + hi) >> 1; if (va[mid] < key) lo = mid + 1; else hi = mid; }
    rarr[(size_t)bh*SS + i] = lo;
  }
}

// K3a: chunk-local prefix sums over sorted ranks (CHK=64). LDS-staged sig/u/v for the chunk.
__global__ __launch_bounds__(320) void k3a_prefix(const float* __restrict__ hpf, const float* __restrict__ u,
                                                  const float* __restrict__ v, const int* __restrict__ sig,
                                                  float* __restrict__ PL, float* __restrict__ CS) {
  int bh = blockIdx.x >> 5;
  int ch = blockIdx.x & (NCH - 1);
  int c = threadIdx.x;
  int b = bh >> 2, hh = bh & 3;
  __shared__ int   js[CHK];
  __shared__ float us[CHK], vs[CHK];
  if (c < CHK) {
    int j = sig[(size_t)bh*SS + ch*CHK + c];
    js[c] = j;
    us[c] = u[(size_t)bh*SS + j];
    vs[c] = v[(size_t)bh*SS + j];
  }
  __syncthreads();
  if (c >= NC) return;
  if (ch == 0) PL[((size_t)bh*2049 + 0)*NC + c] = 0.f;   // rank-0 prefix = 0
  const float* hb = hpf + (size_t)b*SS*HD + hh*DD;
  float acc = 0.f;
  size_t plbase = ((size_t)bh*2049 + ch*CHK + 1)*NC + c;
#pragma unroll 8
  for (int r = 0; r < CHK; ++r) {
    float term;
    if (c < 128)      term = us[r] * hb[(size_t)js[r]*HD + c];
    else if (c < 256) term = vs[r] * hb[(size_t)js[r]*HD + (c-128)];
    else if (c == 256) term = us[r];
    else              term = vs[r];
    acc += term;
    PL[plbase + (size_t)r*NC] = acc;
  }
  CS[((size_t)bh*NCH + ch)*NC + c] = acc;
}

// K4: natural row order; r precomputed (rarr); chunk-offset scan recomputed in LDS from CS
// (replaces k3b and the global O/Tot arrays). Plain coalesced f32x4 attn stores.
__global__ __launch_bounds__(256) void k4_main(const float* __restrict__ e1, const float* __restrict__ m2arr,
                                               const float* __restrict__ u, const float* __restrict__ v,
                                               const float* __restrict__ PL, const float* __restrict__ CS,
                                               const float* __restrict__ abp,
                                               const int* __restrict__ rarr,
                                               float* __restrict__ ctx, float* __restrict__ attn) {
  int bh = blockIdx.x >> 6;      // 64 i-blocks of 32 rows
  int ib = blockIdx.x & 63;
  int b = bh >> 2, hh = bh & 3;
  __shared__ float u_s[SS];
  __shared__ float v_s[SS];
  __shared__ float O_s[NCH][NC];
  __shared__ float tot_s[NC];
  for (int j = threadIdx.x; j < SS; j += 256) {
    u_s[j] = u[(size_t)bh*SS + j];
    v_s[j] = v[(size_t)bh*SS + j];
  }
  for (int c0 = threadIdx.x; c0 < NC; c0 += 256) {
    float acc = 0.f;
#pragma unroll 8
    for (int ch = 0; ch < NCH; ++ch) {
      O_s[ch][c0] = acc;
      acc += CS[((size_t)bh*NCH + ch)*NC + c0];
    }
    tot_s[c0] = acc;
  }
  __syncthreads();
  int wid = threadIdx.x >> 6, lane = threadIdx.x & 63;
  float m2 = m2arr[bh];
  float ab = abp[0];
  float SuT = tot_s[256];
  for (int rr = wid; rr < 32; rr += 4) {
    int i = ib*32 + rr;
    int r = rarr[(size_t)bh*SS + i];
    float t = e1[(size_t)bh*SS + i] + ab + m2;
    float rm = t > 0.f ? t : NSL*t;             // = leakyrelu(t) = exact row max
    float alpha = expf(t - rm);
    float beta  = expf(NSL*t - rm);
    float tau = -t;
    int ch = (r == 0) ? 0 : ((r - 1) >> 6);
    const float* PLrow = PL + ((size_t)bh*2049 + r)*NC;
    const float* Orow  = O_s[ch];
    float SU = PLrow[256] + Orow[256];
    float SV = PLrow[257] + Orow[257];
    float denom = alpha * (SuT - SU) + beta * SV;
    float inv = 1.f / denom;
    float ad = alpha * inv, bd = beta * inv;
    // ctx from prefix lookups
#pragma unroll
    for (int d0 = 0; d0 < 2; ++d0) {
      int d = lane + 64*d0;
      float fu = PLrow[d]       + Orow[d];
      float fv = PLrow[128 + d] + Orow[128 + d];
      float cv = (alpha * (tot_s[d] - fu) + beta * fv) * inv;
      ctx[(size_t)(b*SS + i)*HD + hh*DD + d] = cv;
    }
    float utau = expf(tau);      // piece predicate: u_j >= utau  <=>  delta_j >= tau (monotone)
    float* orow = attn + ((size_t)bh*SS + i)*SS;
#pragma unroll 2
    for (int it = 0; it < 8; ++it) {
      int j0 = it*256 + lane*4;
      f32x4 uu = *(const f32x4*)&u_s[j0];
      f32x4 vv = *(const f32x4*)&v_s[j0];
      f32x4 av;
#pragma unroll
      for (int e = 0; e < 4; ++e) av[e] = (uu[e] >= utau) ? ad*uu[e] : bd*vv[e];
      *(f32x4*)(orow + j0) = av;
    }
  }
}

// K5: out = relu(ctx @ out_w^T + out_b), hi/lo-split bf16 MFMA (~f32 accuracy)
__global__ __launch_bounds__(256) void k5_out(const float* __restrict__ ctx, const float* __restrict__ W2,
                                              const float* __restrict__ b2, float* __restrict__ outp) {
  int wid = threadIdx.x >> 6, lane = threadIdx.x & 63;
  int s0 = blockIdx.x * 16;        // 512 blocks
  int n0 = wid * 32;
  int row = lane & 15, g = lane >> 4;
  const float* pa  = ctx + (size_t)(s0 + row) * HD + g * 8;
  const float* pb0 = W2  + (size_t)(n0 + row) * HD + g * 8;
  const float* pb1 = W2  + (size_t)(n0 + 16 + row) * HD + g * 8;
  f32x4 acc0 = {0.f,0.f,0.f,0.f}, acc1 = {0.f,0.f,0.f,0.f};
  for (int ks = 0; ks < 16; ++ks) {
    bf16x8 ah, al, b0h, b0l, b1h, b1l;
    load8_split(pa  + ks*32, ah,  al);
    load8_split(pb0 + ks*32, b0h, b0l);
    load8_split(pb1 + ks*32, b1h, b1l);
    acc0 = __builtin_amdgcn_mfma_f32_16x16x32_bf16(ah, b0h, acc0, 0,0,0);
    acc0 = __builtin_amdgcn_mfma_f32_16x16x32_bf16(ah, b0l, acc0, 0,0,0);
    acc0 = __builtin_amdgcn_mfma_f32_16x16x32_bf16(al, b0h, acc0, 0,0,0);
    acc1 = __builtin_amdgcn_mfma_f32_16x16x32_bf16(ah, b1h, acc1, 0,0,0);
    acc1 = __builtin_amdgcn_mfma_f32_16x16x32_bf16(ah, b1l, acc1, 0,0,0);
    acc1 = __builtin_amdgcn_mfma_f32_16x16x32_bf16(al, b1h, acc1, 0,0,0);
  }
  int col = lane & 15;
  float bias0 = b2[n0 + col];
  float bias1 = b2[n0 + 16 + col];
#pragma unroll
  for (int r2 = 0; r2 < 4; ++r2) {
    int orow = g*4 + r2;
    float v0 = acc0[r2] + bias0; v0 = v0 > 0.f ? v0 : 0.f;
    float v1 = acc1[r2] + bias1; v1 = v1 > 0.f ? v1 : 0.f;
    outp[(size_t)(s0 + orow)*OUTD + n0 + col]      = v0;
    outp[(size_t)(s0 + orow)*OUTD + n0 + 16 + col] = v1;
  }
}

extern "C" void kernel_launch(void* const* d_in, const int* in_sizes, int n_in,
                              void* d_out, int out_size, void* d_ws, size_t ws_size,
                              hipStream_t stream) {
  const float* h   = (const float*)d_in[0];
  const int* mask  = (const int*)d_in[1];
  const float* Ww  = (const float*)d_in[2];
  const float* Wb  = (const float*)d_in[3];
  const float* aw  = (const float*)d_in[4];
  const float* abp = (const float*)d_in[5];
  const float* W2  = (const float*)d_in[6];
  const float* b2  = (const float*)d_in[7];
  float* ws = (float*)d_ws;
  float* hpf = ws + OFF_HPF;
  float* e1  = ws + OFF_E1;
  float* e2  = ws + OFF_E2;
  float* m2  = ws + OFF_M2;
  float* u   = ws + OFF_U;
  float* v   = ws + OFF_V;
  int*   sig = (int*)(ws + OFF_SIG);
  int*   rarr= (int*)(ws + OFF_RARR);
  float* wv  = ws + OFF_WV;
  float* PL  = ws + OFF_PL;
  float* CS  = ws + OFF_CS;
  float* ctx = ws + OFF_CTX;
  float* outp = (float*)d_out;
  float* attn = outp + (size_t)BB*SS*OUTD;

  k0_wvec<<<8, 128, 0, stream>>>(Ww, aw, wv);
  k2_e<<<2048, 256, 0, stream>>>(h, wv, e1, e2);
  kfused<<<1040, 1024, 0, stream>>>(h, Ww, Wb, hpf, e1, e2, mask, abp, m2, u, v, sig, rarr);
  k3a_prefix<<<BH*NCH, 320, 0, stream>>>(hpf, u, v, sig, PL, CS);
  k4_main<<<BH*64, 256, 0, stream>>>(e1, m2, u, v, PL, CS, abp, rarr, ctx, attn);
  k5_out<<<512, 256, 0, stream>>>(ctx, W2, b2, outp);
}